// Round 3
// baseline (4158.582 us; speedup 1.0000x reference)
//
#include <hip/hip_runtime.h>
#include <stdint.h>

// ---------------------------------------------------------------------------
// Seq2seq decoder: Luong attention + 2-layer LSTM, B=64, T=48, S=48, E=512,
// H=1024. Round 3: single persistent kernel for the 48-step loop with
// hand-rolled device-scope grid barriers (3 phases/step). Setup unchanged
// except LDS padding in gemm64.
// ---------------------------------------------------------------------------

using short8 = __attribute__((ext_vector_type(8))) short;
using f32x4  = __attribute__((ext_vector_type(4))) float;
typedef unsigned short u16;

#define B_  64
#define T_  48
#define S_  48
#define H_  1024
#define E_  512

__device__ __forceinline__ float bf2f(u16 u) {
    union { unsigned int i; float f; } v; v.i = ((unsigned int)u) << 16; return v.f;
}
__device__ __forceinline__ u16 f2bf(float f) {
    union { float f; unsigned int i; } v; v.f = f;
    unsigned int r = v.i + 0x7fff + ((v.i >> 16) & 1);   // RNE
    return (u16)(r >> 16);
}
__device__ __forceinline__ float sigm(float x) { return 1.f / (1.f + __expf(-x)); }

// ---------------- trivial converters ----------------

__global__ void cast_copy(u16* __restrict__ dst, int dld, int doff,
                          const float* __restrict__ src, int sld, int soff,
                          int rows, int colshift) {
    int cols = 1 << colshift;
    int total = rows << colshift;
    for (int i = blockIdx.x * blockDim.x + threadIdx.x; i < total;
         i += gridDim.x * blockDim.x) {
        int r = i >> colshift, c = i & (cols - 1);
        dst[(size_t)r * dld + doff + c] = f2bf(src[(size_t)r * sld + soff + c]);
    }
}

__global__ void transpose_cast(u16* __restrict__ dst, const float* __restrict__ src) {
    int idx = blockIdx.x * blockDim.x + threadIdx.x;   // 1M threads exactly
    int r = idx >> 10, c = idx & 1023;
    dst[idx] = f2bf(src[(size_t)c * 1024 + r]);
}

__global__ void embed_gather(u16* __restrict__ embA, const float* __restrict__ emb,
                             const int* __restrict__ tgt) {
    int row = blockIdx.x;              // t*64 + b
    int t = row >> 6, b = row & 63;
    int id = tgt[b * T_ + t];
    const float* s = emb + (size_t)id * E_;
    u16* d = embA + (size_t)row * E_;
    for (int e = threadIdx.x; e < E_; e += blockDim.x) d[e] = f2bf(s[e]);
}

__global__ void sbias_kernel(float* __restrict__ sbias, const float* __restrict__ enc,
                             const float* __restrict__ b_l) {
    int r = blockIdx.x, lane = threadIdx.x;
    const float* e = enc + (size_t)r * H_;
    float acc = 0.f;
    for (int k = lane; k < H_; k += 64) acc += b_l[k] * e[k];
    for (int o = 32; o; o >>= 1) acc += __shfl_xor(acc, o);
    if (lane == 0) sbias[r] = acc;
}

__global__ void init_state(u16* __restrict__ xa0, u16* __restrict__ xa1,
                           float* __restrict__ c0b, float* __restrict__ c1b,
                           const float* __restrict__ h0, const float* __restrict__ c0) {
    int i = blockIdx.x * blockDim.x + threadIdx.x;   // 131072 exactly
    int l = i >> 16, rem = i & 65535, b = rem >> 10, c = rem & 1023;
    u16 hb = f2bf(h0[i]);
    float cv = c0[i];
    if (l == 0) { xa0[b * 2048 + 1024 + c] = hb; c0b[rem] = cv; }
    else        { xa1[b * 2048 + 1024 + c] = hb; c1b[rem] = cv; }
}

// ---------------- setup GEMM: D[M][N] = A[M][K] * W[N][K]^T + bias ----------
__global__ __launch_bounds__(256) void gemm64(
    const u16* __restrict__ A, const u16* __restrict__ W, u16* __restrict__ D,
    const float* __restrict__ bias1, const float* __restrict__ bias2,
    int N, int Kd)
{
    __shared__ float part[4][64][65];        // padded: kill 4-way bank conflict
    int tid = threadIdx.x, w = tid >> 6, lane = tid & 63;
    int hf = lane >> 4, q = lane & 15;
    int n0 = blockIdx.x * 64, m0 = blockIdx.y * 64;
    int ks = Kd >> 2;
    int kb = w * ks + hf * 8;
    const u16* ap = A + (size_t)(m0 + q) * Kd + kb;
    const u16* wp = W + (size_t)(n0 + q) * Kd + kb;
    f32x4 acc[4][4] = {};
    for (int k0 = 0; k0 < ks; k0 += 32) {
        short8 bf[4], af[4];
#pragma unroll
        for (int n = 0; n < 4; ++n) bf[n] = *(const short8*)(wp + (size_t)n * 16 * Kd + k0);
#pragma unroll
        for (int m = 0; m < 4; ++m) af[m] = *(const short8*)(ap + (size_t)m * 16 * Kd + k0);
#pragma unroll
        for (int m = 0; m < 4; ++m)
#pragma unroll
            for (int n = 0; n < 4; ++n)
                acc[m][n] = __builtin_amdgcn_mfma_f32_16x16x32_bf16(af[m], bf[n], acc[m][n], 0, 0, 0);
    }
#pragma unroll
    for (int m = 0; m < 4; ++m)
#pragma unroll
        for (int n = 0; n < 4; ++n)
#pragma unroll
            for (int r = 0; r < 4; ++r)
                part[w][m * 16 + hf * 4 + r][n * 16 + q] = acc[m][n][r];
    __syncthreads();
#pragma unroll
    for (int k = 0; k < 16; ++k) {
        int o = tid + k * 256;
        int row = o >> 6, col = o & 63;
        float v = part[0][row][col] + part[1][row][col]
                + part[2][row][col] + part[3][row][col];
        if (bias1) v += bias1[n0 + col] + bias2[n0 + col];
        D[(size_t)(m0 + row) * N + n0 + col] = f2bf(v);
    }
}

// ---------------- persistent decoder kernel ---------------------------------

struct PParams {
    const u16* W0cat; const u16* W1cat;
    const u16* preG;
    const float* b_ih1; const float* b_hh1;
    const u16* encW; const u16* encB;
    const float* sbias; const unsigned char* mask;
    u16* XA0; u16* XA1;
    float* c0buf; float* c1buf;
    float* out; float* hn0; float* hn1; float* cn0; float* cn1;
    unsigned* bar;    // counters at [0],[64],[128],[192]; flag at [1024]
};

union SMem {
    float part[8][64][32];                                    // 64 KB (lstm)
    struct { float h1s[1024]; float partS[48][8]; float pr[48];
             float cpart[4][1024]; } at;                      // 22 KB (attn)
};

// device-scope grid barrier: 128 blocks, 4 spread counters + release flag.
// Timeout safety valve: worst case produces a wrong answer, never a hang.
__device__ __forceinline__ void gridbar(unsigned* bar, int ep) {
    __syncthreads();
    if (threadIdx.x == 0) {
        __threadfence();
        __hip_atomic_fetch_add(bar + (blockIdx.x & 3) * 64, 1u,
                               __ATOMIC_RELEASE, __HIP_MEMORY_SCOPE_AGENT);
        if (blockIdx.x == 0) {
            unsigned tgt = (unsigned)ep * 32u;
            for (int c = 0; c < 4; ++c) {
                int spin = 0;
                while (__hip_atomic_load(bar + c * 64, __ATOMIC_ACQUIRE,
                                         __HIP_MEMORY_SCOPE_AGENT) < tgt) {
                    __builtin_amdgcn_s_sleep(2);
                    if (++spin > (1 << 22)) break;
                }
            }
            __hip_atomic_store(bar + 1024, (unsigned)ep,
                               __ATOMIC_RELEASE, __HIP_MEMORY_SCOPE_AGENT);
        } else {
            int spin = 0;
            while (__hip_atomic_load(bar + 1024, __ATOMIC_ACQUIRE,
                                     __HIP_MEMORY_SCOPE_AGENT) < (unsigned)ep) {
                __builtin_amdgcn_s_sleep(2);
                if (++spin > (1 << 22)) break;
            }
        }
    }
    __syncthreads();
}

__device__ __forceinline__ void lstm_body(
    SMem& sm, int blk, int tid,
    const u16* __restrict__ A, const u16* __restrict__ W,
    const u16* __restrict__ preG, const float* __restrict__ bia,
    const float* __restrict__ bib,
    float* __restrict__ cbuf, u16* __restrict__ hA, u16* __restrict__ hB,
    float* __restrict__ outB, int t, int last,
    float* __restrict__ hnO, float* __restrict__ cnO)
{
    int w = tid >> 6, lane = tid & 63, hf = lane >> 4, q = lane & 15;
    int c0 = blk * 8;
    int kb = w * 256 + hf * 8;
    int row0 = (q >> 3) * 1024 + c0 + (q & 7);
    const u16* wp0 = W + (size_t)row0 * 2048 + kb;
    const u16* wp1 = wp0 + (size_t)2048 * 2048;
    const u16* ap  = A + (size_t)q * 2048 + kb;
    // epilogue prefetches (in flight during the K-loop)
    float gpre[4];
#pragma unroll
    for (int k = 0; k < 4; ++k) {
        int o = tid + k * 512, bb = o >> 5, x = o & 31;
        int gr = (x >> 3) * 1024 + c0 + (x & 7);
        gpre[k] = preG ? bf2f(preG[(size_t)bb * 4096 + gr]) : (bia[gr] + bib[gr]);
    }
    int bb2 = tid >> 3, j2 = tid & 7, ccol = c0 + j2;
    float cp = cbuf[bb2 * 1024 + ccol];

    f32x4 acc[4][2] = {};
#pragma unroll
    for (int k0 = 0; k0 < 256; k0 += 32) {
        short8 b0 = *(const short8*)(wp0 + k0);
        short8 b1 = *(const short8*)(wp1 + k0);
#pragma unroll
        for (int m = 0; m < 4; ++m) {
            short8 af = *(const short8*)(ap + (size_t)m * 16 * 2048 + k0);
            acc[m][0] = __builtin_amdgcn_mfma_f32_16x16x32_bf16(af, b0, acc[m][0], 0, 0, 0);
            acc[m][1] = __builtin_amdgcn_mfma_f32_16x16x32_bf16(af, b1, acc[m][1], 0, 0, 0);
        }
    }
#pragma unroll
    for (int m = 0; m < 4; ++m)
#pragma unroll
        for (int n = 0; n < 2; ++n)
#pragma unroll
            for (int r = 0; r < 4; ++r)
                sm.part[w][m * 16 + hf * 4 + r][n * 16 + q] = acc[m][n][r];
    __syncthreads();
    float gv[4];
#pragma unroll
    for (int k = 0; k < 4; ++k) {
        int o = tid + k * 512;
        int bb = o >> 5, x = o & 31;
        float v = 0.f;
#pragma unroll
        for (int w2 = 0; w2 < 8; ++w2) v += sm.part[w2][bb][x];
        gv[k] = v + gpre[k];
    }
    __syncthreads();
#pragma unroll
    for (int k = 0; k < 4; ++k) {
        int o = tid + k * 512;
        sm.part[0][o >> 5][o & 31] = gv[k];
    }
    __syncthreads();
    float ig = sm.part[0][bb2][j2],      fg = sm.part[0][bb2][8 + j2];
    float gg = sm.part[0][bb2][16 + j2], og = sm.part[0][bb2][24 + j2];
    float cnew = sigm(fg) * cp + sigm(ig) * tanhf(gg);
    float hnew = sigm(og) * tanhf(cnew);
    cbuf[bb2 * 1024 + ccol] = cnew;
    u16 hb16 = f2bf(hnew);
    hA[bb2 * 2048 + ccol] = hb16;
    if (hB) hB[bb2 * 2048 + ccol] = hb16;
    if (outB) outB[((size_t)bb2 * T_ + t) * H_ + ccol] = hnew;
    if (last) { hnO[bb2 * 1024 + ccol] = hnew; cnO[bb2 * 1024 + ccol] = cnew; }
}

__global__ void __launch_bounds__(512, 1) decoder_persistent(PParams P) {
    __shared__ SMem sm;
    int tid = threadIdx.x, blk = blockIdx.x;
    int ep = 0;
    for (int t = 0; t < T_; ++t) {
        int p = t & 1, last = (t == T_ - 1);
        u16* xa0c = P.XA0 + (size_t)p * 131072;
        u16* xa0n = P.XA0 + (size_t)(p ^ 1) * 131072;
        u16* xa1c = P.XA1 + (size_t)p * 131072;
        u16* xa1n = P.XA1 + (size_t)(p ^ 1) * 131072;

        // ---- phase ATTN: blocks 0..63, b = blk ----
        if (blk < 64) {
            for (int i = tid; i < H_; i += 512)
                sm.at.h1s[i] = bf2f(xa1c[blk * 2048 + 1024 + i]);
            __syncthreads();
            if (tid < 384) {
                int s = tid >> 3, kg = tid & 7;
                const u16* ew = P.encW + ((size_t)blk * S_ + s) * H_ + kg * 128;
                const float* hp = sm.at.h1s + kg * 128;
                float acc = 0.f;
                for (int k = 0; k < 128; k += 8) {
                    union { short8 v; u16 u[8]; } x;
                    x.v = *(const short8*)(ew + k);
#pragma unroll
                    for (int e = 0; e < 8; ++e) acc += hp[k + e] * bf2f(x.u[e]);
                }
                sm.at.partS[s][kg] = acc;
            }
            __syncthreads();
            if (tid < 64) {
                float v = -3.0e38f;
                if (tid < S_) {
                    v = P.sbias[blk * S_ + tid];
#pragma unroll
                    for (int kg = 0; kg < 8; ++kg) v += sm.at.partS[tid][kg];
                    if (P.mask[blk * S_ + tid]) v = -3.0e38f;
                }
                float mx = v;
                for (int o = 32; o; o >>= 1) mx = fmaxf(mx, __shfl_xor(mx, o));
                float e = (tid < S_) ? __expf(v - mx) : 0.f;
                float sum = e;
                for (int o = 32; o; o >>= 1) sum += __shfl_xor(sum, o);
                if (tid < S_) sm.at.pr[tid] = e / sum;
            }
            __syncthreads();
            {
                int cg = tid & 127, sh = tid >> 7;    // 4 s-chunks of 12
                const u16* eb = P.encB + ((size_t)blk * S_ + sh * 12) * H_ + cg * 8;
                float a8[8] = {};
                for (int s = 0; s < 12; ++s) {
                    float pw = sm.at.pr[sh * 12 + s];
                    union { short8 v; u16 u[8]; } x;
                    x.v = *(const short8*)(eb + (size_t)s * H_);
#pragma unroll
                    for (int e = 0; e < 8; ++e) a8[e] += pw * bf2f(x.u[e]);
                }
#pragma unroll
                for (int e = 0; e < 8; ++e) sm.at.cpart[sh][cg * 8 + e] = a8[e];
            }
            __syncthreads();
            for (int i = tid; i < H_; i += 512) {
                float v = sm.at.cpart[0][i] + sm.at.cpart[1][i]
                        + sm.at.cpart[2][i] + sm.at.cpart[3][i];
                xa0c[blk * 2048 + i] = f2bf(v);
            }
        }
        gridbar(P.bar, ++ep);

        // ---- phase L0: all 128 blocks ----
        lstm_body(sm, blk, tid, xa0c, P.W0cat, P.preG + (size_t)t * 64 * 4096,
                  nullptr, nullptr, P.c0buf, xa1c, xa0n + 1024, nullptr,
                  t, last, P.hn0, P.cn0);
        gridbar(P.bar, ++ep);

        // ---- phase L1: all 128 blocks ----
        lstm_body(sm, blk, tid, xa1c, P.W1cat, nullptr, P.b_ih1, P.b_hh1,
                  P.c1buf, xa1n + 1024, nullptr, P.out,
                  t, last, P.hn1, P.cn1);
        gridbar(P.bar, ++ep);
    }
}

// ---------------------------------------------------------------------------

extern "C" void kernel_launch(void* const* d_in, const int* in_sizes, int n_in,
                              void* d_out, int out_size, void* d_ws, size_t ws_size,
                              hipStream_t stream) {
    const int*   tgt      = (const int*)d_in[0];
    const float* h0       = (const float*)d_in[1];
    const float* c0in     = (const float*)d_in[2];
    const float* enc      = (const float*)d_in[3];
    const unsigned char* mask = (const unsigned char*)d_in[4];
    const float* embedding= (const float*)d_in[5];
    const float* W_l      = (const float*)d_in[6];
    const float* b_l      = (const float*)d_in[7];
    const float* W_ih0    = (const float*)d_in[8];
    const float* W_hh0    = (const float*)d_in[9];
    const float* b_ih0    = (const float*)d_in[10];
    const float* b_hh0    = (const float*)d_in[11];
    const float* W_ih1    = (const float*)d_in[12];
    const float* W_hh1    = (const float*)d_in[13];
    const float* b_ih1    = (const float*)d_in[14];
    const float* b_hh1    = (const float*)d_in[15];
    float* out = (float*)d_out;

    char* ws = (char*)d_ws;
    u16* W0emb = (u16*)ws;               ws += (size_t)4096 * 512 * 2;
    u16* W0cat = (u16*)ws;               ws += (size_t)4096 * 2048 * 2;
    u16* W1cat = (u16*)ws;               ws += (size_t)4096 * 2048 * 2;
    u16* WlT   = (u16*)ws;               ws += (size_t)1024 * 1024 * 2;
    u16* embA  = (u16*)ws;               ws += (size_t)3072 * 512 * 2;
    u16* encB  = (u16*)ws;               ws += (size_t)3072 * 1024 * 2;
    u16* encWb = (u16*)ws;               ws += (size_t)3072 * 1024 * 2;
    float* sbias = (float*)ws;           ws += (size_t)3072 * 4;
    u16* preG  = (u16*)ws;               ws += (size_t)3072 * 4096 * 2;
    u16* XA0   = (u16*)ws;               ws += (size_t)2 * 64 * 2048 * 2;
    u16* XA1   = (u16*)ws;               ws += (size_t)2 * 64 * 2048 * 2;
    float* c0buf = (float*)ws;           ws += (size_t)64 * 1024 * 4;
    float* c1buf = (float*)ws;           ws += (size_t)64 * 1024 * 4;
    unsigned* bar = (unsigned*)ws;       ws += 8192;

    // ---- one-time (per launch) setup ----
    cast_copy<<<2048, 256, 0, stream>>>(W0emb, 512, 0,    W_ih0, 1536, 0,   4096, 9);
    cast_copy<<<2048, 256, 0, stream>>>(W0cat, 2048, 0,   W_ih0, 1536, 512, 4096, 10);
    cast_copy<<<2048, 256, 0, stream>>>(W0cat, 2048, 1024, W_hh0, 1024, 0,  4096, 10);
    cast_copy<<<2048, 256, 0, stream>>>(W1cat, 2048, 0,   W_ih1, 1024, 0,   4096, 10);
    cast_copy<<<2048, 256, 0, stream>>>(W1cat, 2048, 1024, W_hh1, 1024, 0,  4096, 10);
    cast_copy<<<2048, 256, 0, stream>>>(encB, 1024, 0,    enc,   1024, 0,   3072, 10);
    transpose_cast<<<4096, 256, 0, stream>>>(WlT, W_l);
    embed_gather<<<3072, 256, 0, stream>>>(embA, embedding, tgt);
    init_state<<<512, 256, 0, stream>>>(XA0, XA1, c0buf, c1buf, h0, c0in);
    sbias_kernel<<<3072, 64, 0, stream>>>(sbias, enc, b_l);
    gemm64<<<dim3(64, 48), 256, 0, stream>>>(embA, W0emb, preG, b_ih0, b_hh0, 4096, 512);
    gemm64<<<dim3(16, 48), 256, 0, stream>>>(encB, WlT, encWb, nullptr, nullptr, 1024, 1024);
    hipMemsetAsync(bar, 0, 8192, stream);

    PParams prm;
    prm.W0cat = W0cat; prm.W1cat = W1cat; prm.preG = preG;
    prm.b_ih1 = b_ih1; prm.b_hh1 = b_hh1;
    prm.encW = encWb; prm.encB = encB; prm.sbias = sbias; prm.mask = mask;
    prm.XA0 = XA0; prm.XA1 = XA1; prm.c0buf = c0buf; prm.c1buf = c1buf;
    prm.out = out;
    prm.hn0 = out + 3145728; prm.hn1 = out + 3145728 + 65536;
    prm.cn0 = out + 3276800; prm.cn1 = out + 3276800 + 65536;
    prm.bar = bar;
    decoder_persistent<<<128, 512, 0, stream>>>(prm);

    (void)in_sizes; (void)n_in; (void)out_size; (void)ws_size;
}